// Round 1
// baseline (1193.162 us; speedup 1.0000x reference)
//
#include <hip/hip_runtime.h>
#include <math.h>

#define NROWS 8192
#define NF    128
#define THR   0.004f

#define XI_LD 132
#define FJ_LD 132
#define AG_LD 132

__global__ __launch_bounds__(256) void norms_k(const float* __restrict__ feat,
                                               float* __restrict__ inv_norm) {
    int row  = blockIdx.x * 4 + (threadIdx.x >> 6);
    int lane = threadIdx.x & 63;
    const float2* fp = reinterpret_cast<const float2*>(feat + (size_t)row * NF);
    float2 e = fp[lane];
    float ss = e.x * e.x + e.y * e.y;
    #pragma unroll
    for (int off = 32; off; off >>= 1) ss += __shfl_xor(ss, off);
    if (lane == 0) inv_norm[row] = 1.0f / (sqrtf(ss) + 1e-12f);
}

__global__ __launch_bounds__(256) void fused_k(const float* __restrict__ feat,
                                               const float* __restrict__ Wm,
                                               const float* __restrict__ inv_norm,
                                               float* __restrict__ out) {
    __shared__ float sXi[32 * XI_LD];
    __shared__ float sFj[64 * FJ_LD];
    __shared__ float sInvJ[64];
    __shared__ float sAgg[32 * AG_LD];

    const int t = threadIdx.x;
    const int c = t & 7;        // lane group within row: 8 threads per row
    const int r = t >> 3;       // row within i-tile, 0..31
    const int ibase = blockIdx.x * 32;
    const int gi = ibase + r;

    // ---- stage Xi tile (raw features, rows ibase..ibase+31), float4 coalesced
    for (int u = t; u < 32 * 32; u += 256) {
        int row = u >> 5, c4 = u & 31;
        reinterpret_cast<float4*>(sXi + row * XI_LD)[c4] =
            reinterpret_cast<const float4*>(feat + (size_t)(ibase + row) * NF)[c4];
    }
    const float inv_i = inv_norm[gi];

    float4 acc0 = {0,0,0,0}, acc1 = {0,0,0,0}, acc2 = {0,0,0,0}, acc3 = {0,0,0,0};

    for (int jb = 0; jb < NROWS; jb += 64) {
        // ---- stage Fj tile (64 rows) + inv norms
        for (int u = t; u < 64 * 32; u += 256) {
            int row = u >> 5, c4 = u & 31;
            reinterpret_cast<float4*>(sFj + row * FJ_LD)[c4] =
                reinterpret_cast<const float4*>(feat + (size_t)(jb + row) * NF)[c4];
        }
        if (t < 64) sInvJ[t] = inv_norm[jb + t];
        __syncthreads();

        // ---- dot phase: d[s] = dot(F[gi], F[jb + c + 8s]), fp32
        float d[8] = {0,0,0,0,0,0,0,0};
        #pragma unroll 4
        for (int k4 = 0; k4 < 32; ++k4) {
            float4 xi = *reinterpret_cast<const float4*>(sXi + r * XI_LD + 4 * k4);
            #pragma unroll
            for (int s = 0; s < 8; ++s) {
                float4 xj = *reinterpret_cast<const float4*>(sFj + (c + 8 * s) * FJ_LD + 4 * k4);
                d[s] += xi.x * xj.x + xi.y * xj.y + xi.z * xj.z + xi.w * xj.w;
            }
        }

        // ---- threshold + ballot: row-group's 8-bit mask per s-slice
        unsigned mb[8];
        #pragma unroll
        for (int s = 0; s < 8; ++s) {
            int jj = c + 8 * s;
            float v = d[s] * inv_i * sInvJ[jj];
            bool pred = (v * v >= THR) && ((jb + jj) != gi);
            unsigned long long b = __ballot(pred);
            mb[s] = (unsigned)((b >> (8 * (r & 7))) & 0xffu);
        }

        // ---- masked accumulate: acc(row r, feats 4c+32q..+3) += Fj[jj]
        #pragma unroll
        for (int s = 0; s < 8; ++s) {
            unsigned m = mb[s];
            while (m) {
                int c2 = __ffs(m) - 1;
                m &= m - 1;
                const float* fr = sFj + (c2 + 8 * s) * FJ_LD + 4 * c;
                float4 f0 = *reinterpret_cast<const float4*>(fr);
                float4 f1 = *reinterpret_cast<const float4*>(fr + 32);
                float4 f2 = *reinterpret_cast<const float4*>(fr + 64);
                float4 f3 = *reinterpret_cast<const float4*>(fr + 96);
                acc0.x += f0.x; acc0.y += f0.y; acc0.z += f0.z; acc0.w += f0.w;
                acc1.x += f1.x; acc1.y += f1.y; acc1.z += f1.z; acc1.w += f1.w;
                acc2.x += f2.x; acc2.y += f2.y; acc2.z += f2.z; acc2.w += f2.w;
                acc3.x += f3.x; acc3.y += f3.y; acc3.z += f3.z; acc3.w += f3.w;
            }
        }
        __syncthreads();
    }

    // ---- agg tile -> LDS (thread owns feats 4c + 32q)
    *reinterpret_cast<float4*>(sAgg + r * AG_LD + 4 * c)      = acc0;
    *reinterpret_cast<float4*>(sAgg + r * AG_LD + 4 * c + 32) = acc1;
    *reinterpret_cast<float4*>(sAgg + r * AG_LD + 4 * c + 64) = acc2;
    *reinterpret_cast<float4*>(sAgg + r * AG_LD + 4 * c + 96) = acc3;
    __syncthreads();

    // ---- epilogue: out[gi][c + 8*o8] = relu( sum_k agg[r][k] * W[o][k] )
    float sum[16];
    #pragma unroll
    for (int o8 = 0; o8 < 16; ++o8) sum[o8] = 0.f;
    for (int k4 = 0; k4 < 32; ++k4) {
        float4 a4 = *reinterpret_cast<const float4*>(sAgg + r * AG_LD + 4 * k4);
        #pragma unroll
        for (int o8 = 0; o8 < 16; ++o8) {
            float4 w4 = *reinterpret_cast<const float4*>(Wm + (size_t)(c + 8 * o8) * NF + 4 * k4);
            sum[o8] += a4.x * w4.x + a4.y * w4.y + a4.z * w4.z + a4.w * w4.w;
        }
    }
    #pragma unroll
    for (int o8 = 0; o8 < 16; ++o8) {
        float v = sum[o8];
        out[(size_t)gi * NF + c + 8 * o8] = v > 0.f ? v : 0.f;
    }
}

extern "C" void kernel_launch(void* const* d_in, const int* in_sizes, int n_in,
                              void* d_out, int out_size, void* d_ws, size_t ws_size,
                              hipStream_t stream) {
    const float* feat = (const float*)d_in[0];   // [8192,128] f32
    const float* Wm   = (const float*)d_in[1];   // [128,128]  f32
    float* out        = (float*)d_out;           // [8192,128] f32
    float* inv_norm   = (float*)d_ws;            // 8192 f32 scratch

    norms_k<<<NROWS / 4, 256, 0, stream>>>(feat, inv_norm);
    fused_k<<<NROWS / 32, 256, 0, stream>>>(feat, Wm, inv_norm, out);
}

// Round 2
// 218.874 us; speedup vs baseline: 5.4514x; 5.4514x over previous
//
#include <hip/hip_runtime.h>
#include <math.h>

#define NROWS 8192
#define NF    128
#define THRF  0.004f
#define BM    32
#define BN    128

typedef __attribute__((ext_vector_type(8))) short bf16x8;
typedef __attribute__((ext_vector_type(4))) float f32x4;

#define MFMA16(a, b, c) __builtin_amdgcn_mfma_f32_16x16x32_bf16(a, b, c, 0, 0, 0)

__device__ __forceinline__ int swz8(int r) { return ((r ^ (r >> 3)) & 7) << 4; }

__device__ __forceinline__ unsigned short bf16rn(float x) {
    unsigned b = __float_as_uint(x);
    return (unsigned short)((b + 0x7FFFu + ((b >> 16) & 1u)) >> 16);
}
__device__ __forceinline__ float bf16f(unsigned short h) {
    return __uint_as_float(((unsigned)h) << 16);
}

// ---------------- prep: inv_norms + hi/lo bf16 split of X ----------------
__global__ __launch_bounds__(256) void prep_k(const float* __restrict__ X,
                                              float* __restrict__ inv_norm,
                                              unsigned short* __restrict__ Xh,
                                              unsigned short* __restrict__ Xl) {
    int row  = blockIdx.x * 4 + (threadIdx.x >> 6);
    int lane = threadIdx.x & 63;
    float2 e = reinterpret_cast<const float2*>(X + (size_t)row * NF)[lane];
    float ss = e.x * e.x + e.y * e.y;
    #pragma unroll
    for (int off = 32; off; off >>= 1) ss += __shfl_xor(ss, off);
    if (lane == 0) inv_norm[row] = 1.0f / (sqrtf(ss) + 1e-12f);

    unsigned short hx = bf16rn(e.x), hy = bf16rn(e.y);
    unsigned short lx = bf16rn(e.x - bf16f(hx)), ly = bf16rn(e.y - bf16f(hy));
    reinterpret_cast<unsigned*>(Xh)[row * 64 + lane] = (unsigned)hx | ((unsigned)hy << 16);
    reinterpret_cast<unsigned*>(Xl)[row * 64 + lane] = (unsigned)lx | ((unsigned)ly << 16);
}

// ---------------- fused fidelity + threshold + aggregate + W epilogue ----------------
__global__ __launch_bounds__(512) void fused_k(const unsigned short* __restrict__ Xh,
                                               const unsigned short* __restrict__ Xl,
                                               const float* __restrict__ inv_norm,
                                               const float* __restrict__ Wm,
                                               float* __restrict__ out) {
    __shared__ union USh {
        unsigned short tiles[2 * BN * NF];  // sXh | sXl (XOR-swizzled rows), 64 KB
        float w[NF * NF];                   // W staged for epilogue, 64 KB
    } uS;
    __shared__ unsigned short sP[BM * BN];  // adjacency tile, swizzled, 8 KB
    __shared__ float sInvJ[BN];
    __shared__ float sAgg[BM][140];         // stride 140: 2-way max on epilogue reads

    unsigned short* sXh = uS.tiles;
    unsigned short* sXl = uS.tiles + BN * NF;

    const int t   = threadIdx.x;
    const int w   = t >> 6;
    const int l   = t & 63;
    const int l15 = l & 15;
    const int h   = l >> 4;          // 0..3
    const int wm  = w >> 2;          // 0..1  (i band of 16 rows)
    const int wn  = w & 3;           // 0..3  (j / f band of 32)
    const int ibase = blockIdx.x * BM;

    // ---- preload Xi A-fragments (rows ibase + 16*wm + l15), hi and lo
    bf16x8 aH[4], aL[4];
    {
        const size_t ro = (size_t)(ibase + 16 * wm + l15) * NF;
        #pragma unroll
        for (int ks = 0; ks < 4; ++ks) {
            aH[ks] = *reinterpret_cast<const bf16x8*>(Xh + ro + ks * 32 + 8 * h);
            aL[ks] = *reinterpret_cast<const bf16x8*>(Xl + ro + ks * 32 + 8 * h);
        }
    }
    // ---- per-lane threshold constants for C-frag rows (row = 16*wm + 4*h + q)
    float invI[4]; int giq[4];
    #pragma unroll
    for (int q = 0; q < 4; ++q) {
        giq[q]  = ibase + 16 * wm + 4 * h + q;
        invI[q] = inv_norm[giq[q]];
    }

    f32x4 agg[2] = {{0.f, 0.f, 0.f, 0.f}, {0.f, 0.f, 0.f, 0.f}};

    for (int jb = 0; jb < NROWS; jb += BN) {
        // ---- stage j-tile (hi+lo), swizzled rows; 4x16B per thread per tile
        {
            int row = t >> 2, seg = t & 3;
            const unsigned short* gh = Xh + (size_t)(jb + row) * NF + seg * 32;
            const unsigned short* gl = Xl + (size_t)(jb + row) * NF + seg * 32;
            int sw = swz8(row);
            #pragma unroll
            for (int u = 0; u < 4; ++u) {
                int b = row * 256 + seg * 64 + u * 16;
                *reinterpret_cast<bf16x8*>((char*)sXh + (b ^ sw)) =
                    *reinterpret_cast<const bf16x8*>(gh + u * 8);
                *reinterpret_cast<bf16x8*>((char*)sXl + (b ^ sw)) =
                    *reinterpret_cast<const bf16x8*>(gl + u * 8);
            }
            if (t < BN) sInvJ[t] = inv_norm[jb + t];
        }
        __syncthreads();

        // ---- GEMM1: S = Xi . Xj^T  (4-pass hi/lo, fp32-accurate)
        f32x4 S[2] = {{0.f, 0.f, 0.f, 0.f}, {0.f, 0.f, 0.f, 0.f}};
        #pragma unroll
        for (int ks = 0; ks < 4; ++ks) {
            #pragma unroll
            for (int nt = 0; nt < 2; ++nt) {
                int jl = 32 * wn + 16 * nt + l15;
                int b  = (jl * 256 + ks * 64 + 16 * h) ^ swz8(jl);
                bf16x8 bh = *reinterpret_cast<const bf16x8*>((const char*)sXh + b);
                bf16x8 bl = *reinterpret_cast<const bf16x8*>((const char*)sXl + b);
                S[nt] = MFMA16(aH[ks], bh, S[nt]);
                S[nt] = MFMA16(aL[ks], bh, S[nt]);
                S[nt] = MFMA16(aH[ks], bl, S[nt]);
                S[nt] = MFMA16(aL[ks], bl, S[nt]);
            }
        }

        // ---- threshold -> P tile (bf16 one/zero), diagonal masked
        #pragma unroll
        for (int nt = 0; nt < 2; ++nt) {
            int jl = 32 * wn + 16 * nt + l15;
            float invj = sInvJ[jl];
            int gj = jb + jl;
            #pragma unroll
            for (int q = 0; q < 4; ++q) {
                float v = S[nt][q] * invI[q] * invj;
                bool p = (v * v >= THRF) && (giq[q] != gj);
                int il = 16 * wm + 4 * h + q;
                int b  = (il * 256 + jl * 2) ^ swz8(il);
                *reinterpret_cast<unsigned short*>((char*)sP + b) = p ? 0x3F80u : 0u;
            }
        }
        __syncthreads();

        // ---- GEMM2: agg += P . Xj  (single hi pass)
        #pragma unroll
        for (int kj = 0; kj < 4; ++kj) {
            int il = 16 * wm + l15;
            int ab = (il * 256 + kj * 64 + 16 * h) ^ swz8(il);
            bf16x8 pa = *reinterpret_cast<const bf16x8*>((const char*)sP + ab);
            #pragma unroll
            for (int nt2 = 0; nt2 < 2; ++nt2) {
                int f = 32 * wn + 16 * nt2 + l15;
                int c4 = ((4 * kj + h) & 7) << 4;
                int base = ((32 * kj + 8 * h) * 256 + f * 2) ^ c4;
                bf16x8 bx;
                #pragma unroll
                for (int r = 0; r < 8; ++r) {
                    int addr = (base + r * 256) ^ (r << 4);
                    bx[r] = *reinterpret_cast<const short*>((const char*)sXh + addr);
                }
                agg[nt2] = MFMA16(pa, bx, agg[nt2]);
            }
        }
        __syncthreads();
    }

    // ---- epilogue: out = relu(agg @ W^T)
    #pragma unroll
    for (int nt2 = 0; nt2 < 2; ++nt2) {
        #pragma unroll
        for (int q = 0; q < 4; ++q) {
            int il = 16 * wm + 4 * h + q;
            int f  = 32 * wn + 16 * nt2 + l15;
            sAgg[il][f] = agg[nt2][q];
        }
    }
    // stage W over the (no longer needed) tile space
    for (int u = t; u < NF * NF / 4; u += 512) {
        reinterpret_cast<f32x4*>(uS.w)[u] = reinterpret_cast<const f32x4*>(Wm)[u];
    }
    __syncthreads();

    {
        int og = t >> 5, row = t & 31;
        float s[8];
        #pragma unroll
        for (int oi = 0; oi < 8; ++oi) s[oi] = 0.f;
        #pragma unroll 4
        for (int k4 = 0; k4 < 32; ++k4) {
            f32x4 a = *reinterpret_cast<const f32x4*>(&sAgg[row][k4 * 4]);
            #pragma unroll
            for (int oi = 0; oi < 8; ++oi) {
                f32x4 wv = *reinterpret_cast<const f32x4*>(&uS.w[(og * 8 + oi) * NF + k4 * 4]);
                s[oi] += a[0] * wv[0] + a[1] * wv[1] + a[2] * wv[2] + a[3] * wv[3];
            }
        }
        #pragma unroll
        for (int oi = 0; oi < 8; ++oi) {
            float v = s[oi];
            out[(size_t)(ibase + row) * NF + og * 8 + oi] = v > 0.f ? v : 0.f;
        }
    }
}

extern "C" void kernel_launch(void* const* d_in, const int* in_sizes, int n_in,
                              void* d_out, int out_size, void* d_ws, size_t ws_size,
                              hipStream_t stream) {
    const float* feat = (const float*)d_in[0];   // [8192,128] f32
    const float* Wm   = (const float*)d_in[1];   // [128,128]  f32
    float* out        = (float*)d_out;           // [8192,128] f32

    char* ws = (char*)d_ws;
    float* inv_norm       = (float*)ws;                          // 32 KB
    unsigned short* Xh    = (unsigned short*)(ws + 32768);       // 2 MB
    unsigned short* Xl    = (unsigned short*)(ws + 32768 + 2097152);  // 2 MB

    prep_k<<<NROWS / 4, 256, 0, stream>>>(feat, inv_norm, Xh, Xl);
    fused_k<<<NROWS / BM, 512, 0, stream>>>(Xh, Xl, inv_norm, Wm, out);
}

// Round 4
// 121.259 us; speedup vs baseline: 9.8398x; 1.8050x over previous
//
#include <hip/hip_runtime.h>
#include <math.h>

#define NROWS  8192
#define NF     128
#define THRF   0.004f
#define BM     64
#define BN     64
#define HALF_N 4096
#define NITER  64          // HALF_N / BN

typedef _Float16 f16;
typedef __attribute__((ext_vector_type(8))) _Float16 f16x8;
typedef __attribute__((ext_vector_type(4))) float f32x4;

#define MFMA16F(a, b, c) __builtin_amdgcn_mfma_f32_16x16x32_f16(a, b, c, 0, 0, 0)

// ---- LDS byte map (fused_k), 1 block/CU ----
#define RH_OFF 0         // row-major hi tiles, 2 x 16384
#define RL_OFF 32768     // row-major lo tiles, 2 x 16384
#define TB_OFF 65536     // f-major hi tiles,  2 x 16384
#define PB_OFF 98304     // P tile, 8192
#define IJ_OFF 106496    // invJ,  2 x 64 x 4
#define SM_BYTES 107008

typedef __attribute__((address_space(1))) const unsigned int g_u32;
typedef __attribute__((address_space(3))) unsigned int l_u32;

__device__ __forceinline__ void gload16(const void* g, void* l) {
    // wave-uniform LDS base; HW scatters lane i at base + 16*i. Global addr per-lane.
    __builtin_amdgcn_global_load_lds((g_u32*)g, (l_u32*)l, 16, 0, 0);
}

// ---------------- prep: inv_norms + fp16 hi / scaled-lo split ----------------
__global__ __launch_bounds__(256) void prep_k(const float* __restrict__ X,
                                              float* __restrict__ inv_norm,
                                              unsigned short* __restrict__ Xh,
                                              unsigned short* __restrict__ Xl) {
    int row  = blockIdx.x * 4 + (threadIdx.x >> 6);
    int lane = threadIdx.x & 63;
    float2 e = reinterpret_cast<const float2*>(X + (size_t)row * NF)[lane];
    float ss = e.x * e.x + e.y * e.y;
    #pragma unroll
    for (int off = 32; off; off >>= 1) ss += __shfl_xor(ss, off);
    if (lane == 0) inv_norm[row] = 1.0f / (sqrtf(ss) + 1e-12f);

    f16 hx = (f16)e.x, hy = (f16)e.y;
    f16 lx = (f16)((e.x - (float)hx) * 2048.0f);   // scaled lo: avoids fp16 denormals
    f16 ly = (f16)((e.y - (float)hy) * 2048.0f);
    unsigned hu = (unsigned)__builtin_bit_cast(unsigned short, hx) |
                  ((unsigned)__builtin_bit_cast(unsigned short, hy) << 16);
    unsigned lu = (unsigned)__builtin_bit_cast(unsigned short, lx) |
                  ((unsigned)__builtin_bit_cast(unsigned short, ly) << 16);
    reinterpret_cast<unsigned*>(Xh)[row * 64 + lane] = hu;
    reinterpret_cast<unsigned*>(Xl)[row * 64 + lane] = lu;
}

// ---------------- transpose: XhT[f][j] = Xh[j][f]  (FULL 128-feature coverage) ----------------
__global__ __launch_bounds__(256) void transpose_k(const unsigned short* __restrict__ Xh,
                                                   unsigned short* __restrict__ XhT) {
    __shared__ unsigned short sT[128][136];
    const int t  = threadIdx.x;
    const int jb = blockIdx.x * 128;
    {
        int row = t >> 1, half = t & 1;
        const unsigned short* src = Xh + (size_t)(jb + row) * NF + half * 64;
        #pragma unroll
        for (int k = 0; k < 8; ++k)
            *reinterpret_cast<uint4*>(&sT[row][half * 64 + 8 * k]) =
                reinterpret_cast<const uint4*>(src)[k];
    }
    __syncthreads();
    // t>>1 -> f (0..127), t&1 -> which 64-j half. 256 threads cover all 128x128.
    int f = t >> 1, qh = t & 1;
    unsigned um[32];
    #pragma unroll
    for (int m = 0; m < 32; ++m) {
        int j = 64 * qh + 2 * m;
        um[m] = (unsigned)sT[j][f] | ((unsigned)sT[j + 1][f] << 16);
    }
    unsigned* dst = reinterpret_cast<unsigned*>(XhT + (size_t)f * NROWS + jb + 64 * qh);
    #pragma unroll
    for (int m = 0; m < 32; ++m) dst[m] = um[m];
}

// ---------------- staging: ROW hi/lo + T tiles for window jwin into buf ----------------
__device__ __forceinline__ void issue_tiles(const unsigned short* __restrict__ Xh,
                                            const unsigned short* __restrict__ Xl,
                                            const unsigned short* __restrict__ XhT,
                                            char* SM, int w, int l, int jwin, int buf) {
    const int r16 = l >> 4, c16 = l & 15;
    #pragma unroll
    for (int u = 0; u < 2; ++u) {
        int jloc = 8 * w + 4 * u + r16;
        size_t src = (size_t)(jwin + jloc) * NF + ((c16 ^ (jloc & 15)) << 3);
        char* ldsH = SM + RH_OFF + buf * 16384 + (8 * w + 4 * u) * 256;
        char* ldsL = SM + RL_OFF + buf * 16384 + (8 * w + 4 * u) * 256;
        gload16(Xh + src, ldsH);
        gload16(Xl + src, ldsL);
    }
    const int r8 = l >> 3, c8 = l & 7;
    #pragma unroll
    for (int u = 0; u < 2; ++u) {
        int floc = 16 * w + 8 * u + r8;
        const unsigned short* src = XhT + (size_t)floc * NROWS + jwin + ((c8 ^ (floc & 7)) << 3);
        char* ldsT = SM + TB_OFF + buf * 16384 + (16 * w + 8 * u) * 128;
        gload16(src, ldsT);
    }
}

// ---------------- fused: fidelity (fp16 3-pass) + threshold + aggregate ----------------
__global__ __launch_bounds__(512, 1) void fused_k(const unsigned short* __restrict__ Xh,
                                                  const unsigned short* __restrict__ Xl,
                                                  const unsigned short* __restrict__ XhT,
                                                  const float* __restrict__ inv_norm,
                                                  float* __restrict__ pAgg0,
                                                  float* __restrict__ pAgg1) {
    __shared__ __align__(16) char SM[SM_BYTES];
    const int t = threadIdx.x;
    const int w = t >> 6, l = t & 63, l15 = l & 15, h = l >> 4;
    const int wm = w >> 1, wn = w & 1;           // wn doubles as f-band in GEMM2
    const int bid   = blockIdx.x;
    const int ibase = (bid >> 1) * BM;
    const int qoff  = (bid & 1) * HALF_N;
    float* pAgg = (bid & 1) ? pAgg1 : pAgg0;

    // A-fragments (Xi rows), fp16 hi + scaled lo, register resident
    f16x8 aH[4], aL[4];
    const int gia = ibase + 16 * wm + l15;
    #pragma unroll
    for (int ks = 0; ks < 4; ++ks) {
        aH[ks] = *reinterpret_cast<const f16x8*>(Xh + (size_t)gia * NF + 32 * ks + 8 * h);
        aL[ks] = *reinterpret_cast<const f16x8*>(Xl + (size_t)gia * NF + 32 * ks + 8 * h);
    }
    float invI[4]; int gid[4];
    #pragma unroll
    for (int q = 0; q < 4; ++q) {
        gid[q]  = ibase + 16 * wm + 4 * h + q;
        invI[q] = inv_norm[gid[q]];
    }

    // prologue: stage window 0
    issue_tiles(Xh, Xl, XhT, SM, w, l, qoff, 0);
    if (t < BN) ((float*)(SM + IJ_OFF))[t] = inv_norm[qoff + t];

    f32x4 agg[4];
    #pragma unroll
    for (int nf = 0; nf < 4; ++nf)
        #pragma unroll
        for (int q = 0; q < 4; ++q) agg[nf][q] = 0.f;

    for (int it = 0; it < NITER; ++it) {
        const int buf  = it & 1;
        const int jwin = qoff + it * BN;
        __syncthreads();                                   // S_a: ROW/T(it) + invJ ready
        if (it + 1 < NITER) {
            issue_tiles(Xh, Xl, XhT, SM, w, l, jwin + BN, buf ^ 1);
            if (t < BN)
                ((float*)(SM + IJ_OFF))[(buf ^ 1) * BN + t] = inv_norm[jwin + BN + t];
        }
        // ---- GEMM1: S = Xi . Xj^T (hi*hi) + 2^-11 * (hi*lo + lo*hi)
        const char* rh = SM + RH_OFF + buf * 16384;
        const char* rl = SM + RL_OFF + buf * 16384;
        f32x4 Shi[2], Slo[2];
        #pragma unroll
        for (int nt = 0; nt < 2; ++nt)
            #pragma unroll
            for (int q = 0; q < 4; ++q) { Shi[nt][q] = 0.f; Slo[nt][q] = 0.f; }
        #pragma unroll
        for (int ks = 0; ks < 4; ++ks) {
            #pragma unroll
            for (int nt = 0; nt < 2; ++nt) {
                int jl   = 32 * wn + 16 * nt + l15;
                int boff = jl * 256 + (((4 * ks + h) ^ (jl & 15)) << 4);
                f16x8 bh = *reinterpret_cast<const f16x8*>(rh + boff);
                f16x8 bl = *reinterpret_cast<const f16x8*>(rl + boff);
                Shi[nt] = MFMA16F(aH[ks], bh, Shi[nt]);
                Slo[nt] = MFMA16F(aH[ks], bl, Slo[nt]);
                Slo[nt] = MFMA16F(aL[ks], bh, Slo[nt]);
            }
        }
        // ---- threshold -> P (fp16 {0,1}), diagonal masked
        const float* invJ = (const float*)(SM + IJ_OFF) + buf * BN;
        #pragma unroll
        for (int nt = 0; nt < 2; ++nt) {
            int jl = 32 * wn + 16 * nt + l15;
            float ivj = invJ[jl];
            int gj = jwin + jl;
            #pragma unroll
            for (int q = 0; q < 4; ++q) {
                int il  = 16 * wm + 4 * h + q;
                float v = (Shi[nt][q] + Slo[nt][q] * (1.0f / 2048.0f)) * invI[q] * ivj;
                bool p  = (v * v >= THRF) && (gid[q] != gj);
                int pb  = il * 128 + ((jl * 2) ^ ((il & 7) << 4));
                *reinterpret_cast<unsigned short*>(SM + PB_OFF + pb) =
                    p ? (unsigned short)0x3C00 : (unsigned short)0;
            }
        }
        __syncthreads();                                   // S_b: P visible; next tiles drained
        // ---- GEMM2: agg += P . Xj  (B from f-major T tile)
        const char* tbp = SM + TB_OFF + buf * 16384;
        #pragma unroll
        for (int kj = 0; kj < 2; ++kj) {
            int ila = 16 * wm + l15;
            int pab = ila * 128 + ((64 * kj + 16 * h) ^ ((ila & 7) << 4));
            f16x8 pa = *reinterpret_cast<const f16x8*>(SM + PB_OFF + pab);
            #pragma unroll
            for (int nf = 0; nf < 4; ++nf) {
                int f   = 64 * wn + 16 * nf + l15;
                int tbo = f * 128 + ((64 * kj + 16 * h) ^ ((f & 7) << 4));
                f16x8 bt = *reinterpret_cast<const f16x8*>(tbp + tbo);
                agg[nf] = MFMA16F(pa, bt, agg[nf]);
            }
        }
    }
    // ---- store partial agg
    #pragma unroll
    for (int nf = 0; nf < 4; ++nf) {
        int f = 64 * wn + 16 * nf + l15;
        #pragma unroll
        for (int q = 0; q < 4; ++q) {
            int row = ibase + 16 * wm + 4 * h + q;
            pAgg[(size_t)row * NF + f] = agg[nf][q];
        }
    }
}

// ---------------- combine: agg = p0 + p1; out = relu(agg @ W^T) ----------------
__global__ __launch_bounds__(256) void combine_k(const float* __restrict__ pAgg1,
                                                 const float* __restrict__ Wm,
                                                 float* __restrict__ out) {
    __shared__ float sW[NF * NF];      // 64 KB
    __shared__ float sSum[32][132];
    const int t = threadIdx.x;
    const size_t base = (size_t)blockIdx.x * 32 * NF;
    #pragma unroll
    for (int k = 0; k < 16; ++k) {
        int u4 = t + 256 * k;
        reinterpret_cast<f32x4*>(sW)[u4] = reinterpret_cast<const f32x4*>(Wm)[u4];
    }
    #pragma unroll
    for (int k = 0; k < 16; ++k) {
        int u = t + 256 * k;
        float v = out[base + u] + pAgg1[base + u];   // out holds partial 0
        sSum[u >> 7][u & 127] = v;
    }
    __syncthreads();
    const int r = t & 31, og = t >> 5;
    float acc[16];
    #pragma unroll
    for (int oi = 0; oi < 16; ++oi) acc[oi] = 0.f;
    #pragma unroll 8
    for (int k4 = 0; k4 < 32; ++k4) {
        f32x4 a4 = *reinterpret_cast<const f32x4*>(&sSum[r][4 * k4]);
        #pragma unroll
        for (int oi = 0; oi < 16; ++oi) {
            f32x4 w4 = *reinterpret_cast<const f32x4*>(&sW[(og * 16 + oi) * NF + 4 * k4]);
            acc[oi] += a4[0] * w4[0] + a4[1] * w4[1] + a4[2] * w4[2] + a4[3] * w4[3];
        }
    }
    #pragma unroll
    for (int o4 = 0; o4 < 4; ++o4) {
        f32x4 v4;
        #pragma unroll
        for (int e = 0; e < 4; ++e) {
            float v = acc[o4 * 4 + e];
            v4[e] = v > 0.f ? v : 0.f;
        }
        *reinterpret_cast<f32x4*>(out + base + r * NF + og * 16 + o4 * 4) = v4;
    }
}

extern "C" void kernel_launch(void* const* d_in, const int* in_sizes, int n_in,
                              void* d_out, int out_size, void* d_ws, size_t ws_size,
                              hipStream_t stream) {
    const float* feat = (const float*)d_in[0];   // [8192,128] f32
    const float* Wm   = (const float*)d_in[1];   // [128,128]  f32
    float* out        = (float*)d_out;           // [8192,128] f32

    char* ws = (char*)d_ws;
    unsigned short* Xh  = (unsigned short*)(ws);                        // 2 MB
    unsigned short* Xl  = (unsigned short*)(ws + (2u << 20));           // 2 MB
    unsigned short* XhT = (unsigned short*)(ws + (4u << 20));           // 2 MB
    float* inv_norm     = (float*)(ws + (6u << 20));                    // 32 KB
    float* pAgg1        = (float*)(ws + (6u << 20) + 32768);            // 4 MB

    prep_k<<<NROWS / 4, 256, 0, stream>>>(feat, inv_norm, Xh, Xl);
    transpose_k<<<NROWS / 128, 256, 0, stream>>>(Xh, XhT);
    fused_k<<<256, 512, 0, stream>>>(Xh, Xl, XhT, inv_norm, out, pAgg1);
    combine_k<<<NROWS / 32, 256, 0, stream>>>(pAgg1, Wm, out);
}

// Round 5
// 116.535 us; speedup vs baseline: 10.2386x; 1.0405x over previous
//
#include <hip/hip_runtime.h>
#include <math.h>

#define NROWS  8192
#define NF     128
#define THRF   0.004f
#define BM     64
#define BN     64
#define HALF_N 4096
#define NITER  64          // HALF_N / BN

typedef _Float16 f16;
typedef __attribute__((ext_vector_type(8))) _Float16 f16x8;
typedef __attribute__((ext_vector_type(4))) float f32x4;

#define MFMA16F(a, b, c) __builtin_amdgcn_mfma_f32_16x16x32_f16(a, b, c, 0, 0, 0)

// ---- LDS byte map (fused_k), 1 block/CU ----
#define RH_OFF 0         // row-major hi tiles, 2 x 16384
#define RL_OFF 32768     // row-major lo tiles, 2 x 16384
#define TB_OFF 65536     // f-major hi tiles,  2 x 16384
#define PB_OFF 98304     // P tile, 8192
#define IJ_OFF 106496    // invJ^2, 2 x 64 x 4
#define SM_BYTES 107008

typedef __attribute__((address_space(1))) const unsigned int g_u32;
typedef __attribute__((address_space(3))) unsigned int l_u32;

__device__ __forceinline__ void gload16(const void* g, void* l) {
    // wave-uniform LDS base; HW scatters lane i at base + 16*i. Global addr per-lane.
    __builtin_amdgcn_global_load_lds((g_u32*)g, (l_u32*)l, 16, 0, 0);
}

__device__ __forceinline__ unsigned short f16bits(f16 x) {
    return __builtin_bit_cast(unsigned short, x);
}

// ---------------- prep (merged): inv_norms + fp16 hi/lo split + transpose ----------------
// One block owns 64 rows: computes Xh/Xl + norms, then transposes its own hi rows.
__global__ __launch_bounds__(256) void prep_k(const float* __restrict__ X,
                                              float* __restrict__ inv_norm,
                                              unsigned short* __restrict__ Xh,
                                              unsigned short* __restrict__ Xl,
                                              unsigned short* __restrict__ XhT) {
    __shared__ unsigned short sT[64][136];
    const int t  = threadIdx.x;
    const int jb = blockIdx.x * 64;
    const int row = t >> 2, c0 = (t & 3) * 32;   // 4 threads/row, 32 cols each
    const int grow = jb + row;

    float v[32];
    {
        const float* src = X + (size_t)grow * NF + c0;
        #pragma unroll
        for (int k = 0; k < 8; ++k) {
            f32x4 e = *reinterpret_cast<const f32x4*>(src + 4 * k);
            v[4 * k]     = e[0]; v[4 * k + 1] = e[1];
            v[4 * k + 2] = e[2]; v[4 * k + 3] = e[3];
        }
    }
    float ss = 0.f;
    #pragma unroll
    for (int k = 0; k < 32; ++k) ss += v[k] * v[k];
    ss += __shfl_xor(ss, 1);
    ss += __shfl_xor(ss, 2);
    if ((t & 3) == 0) inv_norm[grow] = 1.0f / (sqrtf(ss) + 1e-12f);

    #pragma unroll
    for (int k = 0; k < 4; ++k) {            // 8 elems per k
        unsigned hw[4], lw[4];
        #pragma unroll
        for (int p = 0; p < 4; ++p) {
            float a = v[8 * k + 2 * p], b = v[8 * k + 2 * p + 1];
            f16 ha = (f16)a, hb = (f16)b;
            f16 la = (f16)((a - (float)ha) * 2048.0f);
            f16 lb = (f16)((b - (float)hb) * 2048.0f);
            hw[p] = (unsigned)f16bits(ha) | ((unsigned)f16bits(hb) << 16);
            lw[p] = (unsigned)f16bits(la) | ((unsigned)f16bits(lb) << 16);
        }
        uint4 h4 = {hw[0], hw[1], hw[2], hw[3]};
        uint4 l4 = {lw[0], lw[1], lw[2], lw[3]};
        *reinterpret_cast<uint4*>(Xh + (size_t)grow * NF + c0 + 8 * k) = h4;
        *reinterpret_cast<uint4*>(Xl + (size_t)grow * NF + c0 + 8 * k) = l4;
        unsigned* sp = reinterpret_cast<unsigned*>(&sT[row][c0 + 8 * k]);
        sp[0] = hw[0]; sp[1] = hw[1]; sp[2] = hw[2]; sp[3] = hw[3];
    }
    __syncthreads();
    // transpose: f = t>>1 (0..127), qh = t&1 selects 32-j half
    {
        int f = t >> 1, qh = t & 1;
        unsigned um[16];
        #pragma unroll
        for (int m = 0; m < 16; ++m) {
            int j = 32 * qh + 2 * m;
            um[m] = (unsigned)sT[j][f] | ((unsigned)sT[j + 1][f] << 16);
        }
        unsigned* dst = reinterpret_cast<unsigned*>(XhT + (size_t)f * NROWS + jb + 32 * qh);
        #pragma unroll
        for (int m = 0; m < 16; ++m) dst[m] = um[m];
    }
}

// ---------------- staging: ROW hi/lo + T tiles for window jwin into buf ----------------
__device__ __forceinline__ void issue_tiles(const unsigned short* __restrict__ Xh,
                                            const unsigned short* __restrict__ Xl,
                                            const unsigned short* __restrict__ XhT,
                                            char* SM, int w, int l, int jwin, int buf) {
    const int r16 = l >> 4, c16 = l & 15;
    #pragma unroll
    for (int u = 0; u < 2; ++u) {
        int jloc = 8 * w + 4 * u + r16;
        size_t src = (size_t)(jwin + jloc) * NF + ((c16 ^ (jloc & 15)) << 3);
        char* ldsH = SM + RH_OFF + buf * 16384 + (8 * w + 4 * u) * 256;
        char* ldsL = SM + RL_OFF + buf * 16384 + (8 * w + 4 * u) * 256;
        gload16(Xh + src, ldsH);
        gload16(Xl + src, ldsL);
    }
    const int r8 = l >> 3, c8 = l & 7;
    #pragma unroll
    for (int u = 0; u < 2; ++u) {
        int floc = 16 * w + 8 * u + r8;
        const unsigned short* src = XhT + (size_t)floc * NROWS + jwin + ((c8 ^ (floc & 7)) << 3);
        char* ldsT = SM + TB_OFF + buf * 16384 + (16 * w + 8 * u) * 128;
        gload16(src, ldsT);
    }
}

// ---------------- fused: fidelity (fp16 3-pass) + threshold + aggregate ----------------
__global__ __launch_bounds__(512, 1) void fused_k(const unsigned short* __restrict__ Xh,
                                                  const unsigned short* __restrict__ Xl,
                                                  const unsigned short* __restrict__ XhT,
                                                  const float* __restrict__ inv_norm,
                                                  float* __restrict__ pAgg0,
                                                  float* __restrict__ pAgg1) {
    __shared__ __align__(16) char SM[SM_BYTES];
    const int t = threadIdx.x;
    const int w = t >> 6, l = t & 63, l15 = l & 15, h = l >> 4;
    const int im = w >> 2;           // 0..1: 32-row i band (GEMM1 + GEMM2)
    const int jn = w & 3;            // 0..3: 16-j band (GEMM1) / 32-f band (GEMM2)
    const int bid   = blockIdx.x;
    const int ibase = (bid >> 1) * BM;
    const int qoff  = (bid & 1) * HALF_N;
    float* pAgg = (bid & 1) ? pAgg1 : pAgg0;

    // A-fragments: 2 i-subtiles x 4 k-steps, hi + scaled-lo, register resident
    f16x8 aH[8], aL[8];
    #pragma unroll
    for (int ii = 0; ii < 2; ++ii)
        #pragma unroll
        for (int ks = 0; ks < 4; ++ks) {
            size_t ro = (size_t)(ibase + 32 * im + 16 * ii + l15) * NF + 32 * ks + 8 * h;
            aH[ii * 4 + ks] = *reinterpret_cast<const f16x8*>(Xh + ro);
            aL[ii * 4 + ks] = *reinterpret_cast<const f16x8*>(Xl + ro);
        }
    float invI2[8];
    #pragma unroll
    for (int ii = 0; ii < 2; ++ii)
        #pragma unroll
        for (int q = 0; q < 4; ++q) {
            float x = inv_norm[ibase + 32 * im + 16 * ii + 4 * h + q];
            invI2[ii * 4 + q] = x * x;
        }
    const int jl = 16 * jn + l15;    // GEMM1 B column (constant per thread)

    // prologue: stage window 0 + invJ^2
    issue_tiles(Xh, Xl, XhT, SM, w, l, qoff, 0);
    if (t < BN) { float x = inv_norm[qoff + t]; ((float*)(SM + IJ_OFF))[t] = x * x; }

    f32x4 agg00 = {0,0,0,0}, agg01 = {0,0,0,0}, agg10 = {0,0,0,0}, agg11 = {0,0,0,0};

    for (int it = 0; it < NITER; ++it) {
        const int buf  = it & 1;
        const int jwin = qoff + it * BN;
        __syncthreads();                                   // S_a: tiles(it) + invJ2 ready (vmcnt drained)
        if (it + 1 < NITER) {
            issue_tiles(Xh, Xl, XhT, SM, w, l, jwin + BN, buf ^ 1);
            if (t < BN) {
                float x = inv_norm[jwin + BN + t];
                ((float*)(SM + IJ_OFF))[(buf ^ 1) * BN + t] = x * x;
            }
        }
        // ---- GEMM1: S = Xi . Xj^T (hi*hi) + 2^-11 * (hi*lo + lo*hi)
        const char* rh = SM + RH_OFF + buf * 16384;
        const char* rl = SM + RL_OFF + buf * 16384;
        f32x4 Shi0 = {0,0,0,0}, Shi1 = {0,0,0,0};
        f32x4 SA0  = {0,0,0,0}, SA1  = {0,0,0,0};
        f32x4 SB0  = {0,0,0,0}, SB1  = {0,0,0,0};
        __builtin_amdgcn_s_setprio(1);
        #pragma unroll
        for (int ks = 0; ks < 4; ++ks) {
            int boff = jl * 256 + (((4 * ks + h) ^ (jl & 15)) << 4);
            f16x8 bh = *reinterpret_cast<const f16x8*>(rh + boff);
            f16x8 bl = *reinterpret_cast<const f16x8*>(rl + boff);
            Shi0 = MFMA16F(aH[ks],     bh, Shi0);
            Shi1 = MFMA16F(aH[4 + ks], bh, Shi1);
            SA0  = MFMA16F(aH[ks],     bl, SA0);
            SA1  = MFMA16F(aH[4 + ks], bl, SA1);
            SB0  = MFMA16F(aL[ks],     bh, SB0);
            SB1  = MFMA16F(aL[4 + ks], bh, SB1);
        }
        __builtin_amdgcn_s_setprio(0);
        // ---- threshold -> P (f16 {0,1}), diagonal masked
        {
            float ij2v = ((const float*)(SM + IJ_OFF))[buf * BN + jl];
            int ecmp = (jwin + jl) - (ibase + 32 * im + 4 * h);
            #pragma unroll
            for (int q = 0; q < 4; ++q) {     // ii = 0
                float vv = Shi0[q] + (SA0[q] + SB0[q]) * (1.0f / 2048.0f);
                float t2 = vv * vv * invI2[q] * ij2v;
                bool p = (t2 >= THRF) && (ecmp != q);
                int il = 32 * im + 4 * h + q;
                int pb = il * 128 + ((jl * 2) ^ ((il & 7) << 4));
                *reinterpret_cast<unsigned short*>(SM + PB_OFF + pb) =
                    p ? (unsigned short)0x3C00 : (unsigned short)0;
            }
            #pragma unroll
            for (int q = 0; q < 4; ++q) {     // ii = 1
                float vv = Shi1[q] + (SA1[q] + SB1[q]) * (1.0f / 2048.0f);
                float t2 = vv * vv * invI2[4 + q] * ij2v;
                bool p = (t2 >= THRF) && (ecmp != 16 + q);
                int il = 32 * im + 16 + 4 * h + q;
                int pb = il * 128 + ((jl * 2) ^ ((il & 7) << 4));
                *reinterpret_cast<unsigned short*>(SM + PB_OFF + pb) =
                    p ? (unsigned short)0x3C00 : (unsigned short)0;
            }
        }
        // S_b (light): P visible (lgkm drained); prefetch DMA stays in flight
        asm volatile("s_waitcnt lgkmcnt(0)\n\ts_barrier" ::: "memory");
        // ---- GEMM2: agg += P . Xj  (A = P rows, B = f-major T tile)
        const char* tbp = SM + TB_OFF + buf * 16384;
        __builtin_amdgcn_s_setprio(1);
        #pragma unroll
        for (int kj = 0; kj < 2; ++kj) {
            int il0 = 32 * im + l15, il1 = il0 + 16;
            f16x8 pa0 = *reinterpret_cast<const f16x8*>(
                SM + PB_OFF + il0 * 128 + ((64 * kj + 16 * h) ^ ((il0 & 7) << 4)));
            f16x8 pa1 = *reinterpret_cast<const f16x8*>(
                SM + PB_OFF + il1 * 128 + ((64 * kj + 16 * h) ^ ((il1 & 7) << 4)));
            int f0 = 32 * jn + l15, f1 = f0 + 16;
            f16x8 bt0 = *reinterpret_cast<const f16x8*>(
                tbp + f0 * 128 + ((64 * kj + 16 * h) ^ ((f0 & 7) << 4)));
            f16x8 bt1 = *reinterpret_cast<const f16x8*>(
                tbp + f1 * 128 + ((64 * kj + 16 * h) ^ ((f1 & 7) << 4)));
            agg00 = MFMA16F(pa0, bt0, agg00);
            agg01 = MFMA16F(pa0, bt1, agg01);
            agg10 = MFMA16F(pa1, bt0, agg10);
            agg11 = MFMA16F(pa1, bt1, agg11);
        }
        __builtin_amdgcn_s_setprio(0);
    }
    // ---- store partial agg: rows 32*im+16*ii+4*h+q, cols 32*jn+16*ff+l15
    #pragma unroll
    for (int q = 0; q < 4; ++q) {
        int r0 = ibase + 32 * im + 4 * h + q;
        int r1 = r0 + 16;
        int c0 = 32 * jn + l15, c1 = c0 + 16;
        pAgg[(size_t)r0 * NF + c0] = agg00[q];
        pAgg[(size_t)r0 * NF + c1] = agg01[q];
        pAgg[(size_t)r1 * NF + c0] = agg10[q];
        pAgg[(size_t)r1 * NF + c1] = agg11[q];
    }
}

// ---------------- combine: agg = p0 + p1; out = relu(agg @ W^T) ----------------
__global__ __launch_bounds__(256) void combine_k(const float* __restrict__ pAgg1,
                                                 const float* __restrict__ Wm,
                                                 float* __restrict__ out) {
    __shared__ float sW[NF * NF];      // 64 KB
    __shared__ float sSum[32][132];
    const int t = threadIdx.x;
    const size_t base = (size_t)blockIdx.x * 32 * NF;
    #pragma unroll
    for (int k = 0; k < 16; ++k) {
        int u4 = t + 256 * k;
        reinterpret_cast<f32x4*>(sW)[u4] = reinterpret_cast<const f32x4*>(Wm)[u4];
    }
    #pragma unroll
    for (int k = 0; k < 16; ++k) {
        int u = t + 256 * k;
        float v = out[base + u] + pAgg1[base + u];   // out holds partial 0
        sSum[u >> 7][u & 127] = v;
    }
    __syncthreads();
    const int r = t & 31, og = t >> 5;
    float acc[16];
    #pragma unroll
    for (int oi = 0; oi < 16; ++oi) acc[oi] = 0.f;
    #pragma unroll 8
    for (int k4 = 0; k4 < 32; ++k4) {
        f32x4 a4 = *reinterpret_cast<const f32x4*>(&sSum[r][4 * k4]);
        #pragma unroll
        for (int oi = 0; oi < 16; ++oi) {
            f32x4 w4 = *reinterpret_cast<const f32x4*>(&sW[(og * 16 + oi) * NF + 4 * k4]);
            acc[oi] += a4[0] * w4[0] + a4[1] * w4[1] + a4[2] * w4[2] + a4[3] * w4[3];
        }
    }
    #pragma unroll
    for (int o4 = 0; o4 < 4; ++o4) {
        f32x4 v4;
        #pragma unroll
        for (int e = 0; e < 4; ++e) {
            float v = acc[o4 * 4 + e];
            v4[e] = v > 0.f ? v : 0.f;
        }
        *reinterpret_cast<f32x4*>(out + base + r * NF + og * 16 + o4 * 4) = v4;
    }
}

extern "C" void kernel_launch(void* const* d_in, const int* in_sizes, int n_in,
                              void* d_out, int out_size, void* d_ws, size_t ws_size,
                              hipStream_t stream) {
    const float* feat = (const float*)d_in[0];   // [8192,128] f32
    const float* Wm   = (const float*)d_in[1];   // [128,128]  f32
    float* out        = (float*)d_out;           // [8192,128] f32

    char* ws = (char*)d_ws;
    unsigned short* Xh  = (unsigned short*)(ws);                        // 2 MB
    unsigned short* Xl  = (unsigned short*)(ws + (2u << 20));           // 2 MB
    unsigned short* XhT = (unsigned short*)(ws + (4u << 20));           // 2 MB
    float* inv_norm     = (float*)(ws + (6u << 20));                    // 32 KB
    float* pAgg1        = (float*)(ws + (6u << 20) + 32768);            // 4 MB

    prep_k<<<NROWS / 64, 256, 0, stream>>>(feat, inv_norm, Xh, Xl, XhT);
    fused_k<<<256, 512, 0, stream>>>(Xh, Xl, XhT, inv_norm, out, pAgg1);
    combine_k<<<NROWS / 32, 256, 0, stream>>>(pAgg1, Wm, out);
}